// Round 5
// baseline (17.720 us; speedup 1.0000x reference)
//
#include <hip/hip_runtime.h>
#include <math.h>

// Siddon exact forward projector — incremental (Amanatides-Woo) traversal.
// Block = 512 threads = 8 waves = 64 consecutive rays x 8 t-sub-ranges.
// Round-4 changes:
//  * 1-deep software pipeline on the volume gather: the next segment's
//    address depends only on DDA state, so the load for segment i+1 is
//    issued BEFORE the fma consuming segment i's value -> waitcnt lands a
//    full iteration after issue, hiding L2/L3 latency across 8 waves/SIMD.
//  * XCD-aware block swizzle: bid%8 (the XCD) owns a contiguous chunk of
//    detector rows, so each XCD's 4 MB L2 caches only a ~2 MB volume wedge
//    instead of thrashing on the full 8 MB volume.

constexpr int      NV    = 128;
constexpr int      NVSQ  = NV * NV;
constexpr unsigned NV3   = (unsigned)NV * NV * NV;
constexpr float    EPS_F = 1e-12f;
constexpr float    BIG_F = 1e9f;
constexpr int      SPLIT = 8;    // sub-ranges per ray = waves per block
constexpr int      RPB   = 64;   // rays per block (= lanes per wave)

__global__ __launch_bounds__(512)
void siddon_fwd_kernel(const float* __restrict__ vol,
                       const float* __restrict__ Mptr,
                       const float* __restrict__ bptr,
                       const float* __restrict__ src,
                       const float* __restrict__ dst,
                       float* __restrict__ out,
                       int n_ray)
{
    int lane = threadIdx.x & 63;
    int sub  = threadIdx.x >> 6;            // 0..7, one sub-range per wave

    // ---- XCD-aware block swizzle (bijective when gridDim.x % 8 == 0) ----
    int bid = blockIdx.x;
    int nwg = gridDim.x;
    int lb  = ((nwg & 7) == 0) ? ((bid & 7) * (nwg >> 3) + (bid >> 3)) : bid;

    int r = lb * RPB + lane;
    bool active = (r < n_ray);
    int rc = active ? r : (n_ray - 1);      // clamped for loads

    // ---- uniform: M inverse via adjugate ----
    float m00 = Mptr[0], m01 = Mptr[1], m02 = Mptr[2];
    float m10 = Mptr[3], m11 = Mptr[4], m12 = Mptr[5];
    float m20 = Mptr[6], m21 = Mptr[7], m22 = Mptr[8];
    float det = m00*(m11*m22 - m12*m21) - m01*(m10*m22 - m12*m20)
              + m02*(m10*m21 - m11*m20);
    float idet = 1.0f / det;
    float i00 =  (m11*m22 - m12*m21)*idet;
    float i01 = -(m01*m22 - m02*m21)*idet;
    float i02 =  (m01*m12 - m02*m11)*idet;
    float i10 = -(m10*m22 - m12*m20)*idet;
    float i11 =  (m00*m22 - m02*m20)*idet;
    float i12 = -(m00*m12 - m02*m10)*idet;
    float i20 =  (m10*m21 - m11*m20)*idet;
    float i21 = -(m00*m21 - m01*m20)*idet;
    float i22 =  (m00*m11 - m01*m10)*idet;

    float bx = bptr[0], by = bptr[1], bz = bptr[2];

    float sxw = src[3*rc+0], syw = src[3*rc+1], szw = src[3*rc+2];
    float exw = dst[3*rc+0], eyw = dst[3*rc+1], ezw = dst[3*rc+2];

    float wxw = exw - sxw, wyw = eyw - syw, wzw = ezw - szw;
    float ray_len = sqrtf(wxw*wxw + wyw*wyw + wzw*wzw);

    float ux = sxw - bx, uy = syw - by, uz = szw - bz;
    float p0x = i00*ux + i01*uy + i02*uz;
    float p0y = i10*ux + i11*uy + i12*uz;
    float p0z = i20*ux + i21*uy + i22*uz;
    float vx = exw - bx, vy = eyw - by, vz = ezw - bz;
    float p1x = i00*vx + i01*vy + i02*vz;
    float p1y = i10*vx + i11*vy + i12*vz;
    float p1z = i20*vx + i21*vy + i22*vz;

    float dx = p1x - p0x, dy = p1y - p0y, dz = p1z - p0z;

    bool parx = fabsf(dx) < EPS_F;
    bool pary = fabsf(dy) < EPS_F;
    bool parz = fabsf(dz) < EPS_F;

    // ---- slab intersection ----
    float tmin = 0.0f, tmax = 1.0f;
    if (parx) {
        bool inside = (p0x >= 0.0f) && (p0x <= (float)NV);
        tmin = fmaxf(tmin, inside ? 0.0f : BIG_F);
        tmax = fminf(tmax, inside ? 1.0f : -BIG_F);
    } else {
        float t0 = (0.0f - p0x) / dx, t1 = ((float)NV - p0x) / dx;
        tmin = fmaxf(tmin, fminf(t0, t1));
        tmax = fminf(tmax, fmaxf(t0, t1));
    }
    if (pary) {
        bool inside = (p0y >= 0.0f) && (p0y <= (float)NV);
        tmin = fmaxf(tmin, inside ? 0.0f : BIG_F);
        tmax = fminf(tmax, inside ? 1.0f : -BIG_F);
    } else {
        float t0 = (0.0f - p0y) / dy, t1 = ((float)NV - p0y) / dy;
        tmin = fmaxf(tmin, fminf(t0, t1));
        tmax = fminf(tmax, fmaxf(t0, t1));
    }
    if (parz) {
        bool inside = (p0z >= 0.0f) && (p0z <= (float)NV);
        tmin = fmaxf(tmin, inside ? 0.0f : BIG_F);
        tmax = fminf(tmax, inside ? 1.0f : -BIG_F);
    } else {
        float t0 = (0.0f - p0z) / dz, t1 = ((float)NV - p0z) / dz;
        tmin = fmaxf(tmin, fminf(t0, t1));
        tmax = fminf(tmax, fmaxf(t0, t1));
    }

    float acc = 0.0f;

    if (active && (tmax > tmin)) {
        float span = (tmax - tmin) * (1.0f / (float)SPLIT);
        float ta = tmin + (float)sub * span;
        float tb = (sub == SPLIT - 1) ? tmax : (tmin + (float)(sub + 1) * span);

        // ---- DDA init at t = ta ----
        float tx = BIG_F, ty = BIG_F, tz = BIG_F;
        float adx = 0.0f, ady = 0.0f, adz = 0.0f;
        int ix, iy, iz;
        int ox = 0, oy = 0, oz = 0;

        if (!parx) {
            float invx = 1.0f / dx;
            adx = fabsf(invx);
            float q = p0x + ta * dx;
            int pl;
            if (dx > 0.0f) { pl = (int)floorf(q) + 1; ix = pl - 1; ox =  NVSQ; }
            else           { pl = (int)ceilf(q)  - 1; ix = pl;     ox = -NVSQ; }
            tx = ((float)pl - p0x) * invx;
        } else {
            ix = (int)floorf(p0x);
        }
        if (!pary) {
            float invy = 1.0f / dy;
            ady = fabsf(invy);
            float q = p0y + ta * dy;
            int pl;
            if (dy > 0.0f) { pl = (int)floorf(q) + 1; iy = pl - 1; oy =  NV; }
            else           { pl = (int)ceilf(q)  - 1; iy = pl;     oy = -NV; }
            ty = ((float)pl - p0y) * invy;
        } else {
            iy = (int)floorf(p0y);
        }
        if (!parz) {
            float invz = 1.0f / dz;
            adz = fabsf(invz);
            float q = p0z + ta * dz;
            int pl;
            if (dz > 0.0f) { pl = (int)floorf(q) + 1; iz = pl - 1; oz =  1; }
            else           { pl = (int)ceilf(q)  - 1; iz = pl;     oz = -1; }
            tz = ((float)pl - p0z) * invz;
        } else {
            iz = (int)floorf(p0z);
        }

        int flat = ix * NVSQ + iy * NV + iz;

        // ---- software-pipelined traversal: load i+1 issued before fma of i ----
        unsigned uf0 = (unsigned)flat;
        bool vok = (uf0 < NV3);
        float vld = vol[vok ? uf0 : 0u];

        float tcur = ta;
        const int MAXIT = 3 * (NV + 1) / SPLIT + 32;   // uniform bound -> SALU loop

        for (int it = 0; it < MAXIT; ++it) {
            if (!(tcur < tb)) break;

            float tn = fminf(fminf(tx, ty), fminf(tz, tb));  // v_min3
            float dt = tn - tcur;

            bool sx = (tx <= tn), sy = (ty <= tn), sz = (tz <= tn);
            tx += sx ? adx : 0.0f;
            ty += sy ? ady : 0.0f;
            tz += sz ? adz : 0.0f;
            flat += (sx ? ox : 0) + (sy ? oy : 0) + (sz ? oz : 0);

            unsigned ufn = (unsigned)flat;
            bool vokn = (ufn < NV3);
            float vldn = vol[vokn ? ufn : 0u];   // issue next gather EARLY

            acc = fmaf(dt, vok ? vld : 0.0f, acc);  // consume PREVIOUS gather

            vld = vldn;
            vok = vokn;
            tcur = tn;
        }
    }

    // ---- block reduction over the 8 sub-ranges: LDS [8][64], conflict-free ----
    __shared__ float part[SPLIT][RPB];
    part[sub][lane] = acc;
    __syncthreads();

    if (threadIdx.x < RPB && active) {
        float s = 0.0f;
        #pragma unroll
        for (int w = 0; w < SPLIT; ++w) s += part[w][threadIdx.x];
        out[r] = s * ray_len;
    }
}

extern "C" void kernel_launch(void* const* d_in, const int* in_sizes, int n_in,
                              void* d_out, int out_size, void* d_ws, size_t ws_size,
                              hipStream_t stream) {
    const float* vol  = (const float*)d_in[0];
    const float* M    = (const float*)d_in[1];
    const float* bvec = (const float*)d_in[2];
    const float* src  = (const float*)d_in[3];
    const float* dst  = (const float*)d_in[4];
    float* out = (float*)d_out;

    int n_ray = in_sizes[3] / 3;
    int nblk = (n_ray + RPB - 1) / RPB;
    dim3 block(512);
    dim3 grid((unsigned)nblk);
    hipLaunchKernelGGL(siddon_fwd_kernel, grid, block, 0, stream,
                       vol, M, bvec, src, dst, out, n_ray);
}